// Round 5
// baseline (12453.131 us; speedup 1.0000x reference)
//
#include <hip/hip_runtime.h>
#include <hip/hip_bf16.h>

// LSTM decoder B=256, T=512, H=1024 — persistent split-bf16 MFMA, v3.
// vs v2: (a) h reads are plain L2-cached loads; coherence via per-step
//   acquire-agent fence (s_waitcnt + buffer_inv) after the group barrier —
//   8 jt-WGs per (XCD, m-group) now share one L2 fetch of the same A tile.
// (b) W_lo LDS staging rewritten wave-contiguous (16 B/lane): conflict-free.
// h writes remain agent-scope relaxed atomics (LLC-visible before barrier count).

#define BB 256
#define TT 512
#define HH 1024

typedef __attribute__((ext_vector_type(8))) short short8;
typedef __attribute__((ext_vector_type(4))) float float4v;

#define MFMA(a, b, c) __builtin_amdgcn_mfma_f32_16x16x32_bf16((a), (b), (c), 0, 0, 0)

#define WP_CPOFF ((size_t)4194304)   // shorts per W plane: 64jt*4g*32ks*64lane*8
#define HP_U64   ((size_t)131072)    // u64 per h buffer: 16blk*32ks*4p*64lane

__device__ __forceinline__ float sigf(float x) { return 1.0f / (1.0f + __expf(-x)); }
__device__ __forceinline__ float tanhff(float x) {
    return 1.0f - 2.0f / (__expf(2.0f * x) + 1.0f);
}
__device__ __forceinline__ unsigned short f2bf(float x) {
    __hip_bfloat16 b = __float2bfloat16(x);
    return __builtin_bit_cast(unsigned short, b);
}
__device__ __forceinline__ float bf2f(unsigned short u) {
    __hip_bfloat16 b = __builtin_bit_cast(__hip_bfloat16, u);
    return __bfloat162float(b);
}

// ---- pack W_hh (4096x1024 f32) into fragment-ordered bf16 hi/lo planes ----
// Wp[cp][jt(64)][g(4)][ks(32)][lane(64)][8]
__global__ __launch_bounds__(256) void pack_w(const float* __restrict__ W_hh,
                                              unsigned short* __restrict__ Wp) {
    int gid = blockIdx.x * 256 + threadIdx.x;   // 0..524287
    int lane = gid & 63;
    int ks = (gid >> 6) & 31;
    int g = (gid >> 11) & 3;
    int jt = (gid >> 13) & 63;
    int r = g * HH + jt * 16 + (lane & 15);
    int k = ks * 32 + (lane >> 4) * 8;
    const float* src = W_hh + (size_t)r * HH + k;
    size_t base = ((((size_t)jt * 4 + g) * 32 + ks) * 64 + lane) * 8;
#pragma unroll
    for (int e = 0; e < 8; ++e) {
        float v = src[e];
        unsigned short hi = f2bf(v);
        Wp[base + e] = hi;
        Wp[WP_CPOFF + base + e] = f2bf(v - bf2f(hi));
    }
}

// ---- h0 -> packed fragment layout in buffer 0; zero barrier counters ----
__global__ __launch_bounds__(256) void prep_state(const float* __restrict__ h0,
                                                  unsigned int* __restrict__ hb0,
                                                  unsigned int* __restrict__ cnt) {
    int gid = blockIdx.x * 256 + threadIdx.x;   // 0..262143
    int r = gid >> 10, k = gid & 1023;
    float v = h0[gid];
    unsigned short hi = f2bf(v);
    unsigned short lo = f2bf(v - bf2f(hi));
    unsigned int word = (unsigned int)hi | ((unsigned int)lo << 16);
    int blk = ((r >> 6) << 2) | ((r >> 4) & 3);
    int l = (r & 15) + (((k & 31) >> 3) << 4);
    size_t idx64 = (((size_t)blk * 32 + (k >> 5)) * 4 + ((k & 7) >> 1)) * 64 + l;
    hb0[idx64 * 2 + (k & 1)] = word;
    if (blockIdx.x == 0 && threadIdx.x < 128) cnt[threadIdx.x] = 0;
}

// ---- persistent LSTM kernel: all 512 steps + final FC ----
__global__ __launch_bounds__(512, 1) void lstm_persist(
    const float* __restrict__ y_hist,
    const float* __restrict__ W_ih,           // (4096) flat
    const float* __restrict__ b_ih,
    const float* __restrict__ b_hh,
    const float* __restrict__ c0,             // (B,H) f32
    const float* __restrict__ W_fc,           // (H)
    const float* __restrict__ b_fc,           // (1)
    const unsigned short* __restrict__ Wp,    // packed hi/lo planes
    unsigned long long* hbase,                // 2 buffers x HP_U64 u64
    unsigned int* cnt,
    float* __restrict__ out)
{
    __shared__ unsigned short Whi[65536];      // 128 KB persistent W_hi slice
    __shared__ __align__(16) unsigned short Wls[2][8192];  // 2 x 16 KB W_lo dbuf
    // 160 KiB exactly -> 1 WG/CU, grid=256 => all WGs co-resident

    const int tid = threadIdx.x;
    const int lane = tid & 63;
    const int wv = tid >> 6;
    const int wv_m = wv & 3;                   // m-subtile (16 rows)
    const int wv_k = wv >> 2;                  // K half
    const int bid = blockIdx.x;
    const int jt = ((bid & 7) << 3) | ((bid >> 3) & 7);  // XCD-swizzled j-tile
    const int gm = bid >> 6;                   // m-group 0..3
    const int m0 = gm << 6;

    // --- persistent W_hi slice -> LDS (coalesced b128) ---
    const unsigned short* WhiG = Wp + (size_t)jt * 65536;
    for (int i = tid; i < 8192; i += 512)
        *(short8*)&Whi[(size_t)i * 8] = *(const short8*)(WhiG + (size_t)i * 8);

    // --- W_lo staging: wave wv stages fragments {2wv, 2wv+1}, 16 B per lane ---
    // fragment fi -> (swk=fi>>3, sg=(fi>>1)&3, sksl=fi&1); LDS off = fi*512 shorts
    const unsigned short* WloG = Wp + WP_CPOFF + (size_t)jt * 65536;
    size_t sgoff[2];  // global short offset (excl. iter term)
    int sloff[2];     // LDS short offset
#pragma unroll
    for (int p = 0; p < 2; ++p) {
        int fi = wv * 2 + p;
        sgoff[p] = (size_t)((((fi >> 1) & 3) * 32 + (fi >> 3) * 16 + (fi & 1)) * 512) + lane * 8;
        sloff[p] = fi * 512 + lane * 8;
    }

    // --- A addressing: u64 block base for (gm, wv_m) ---
    const size_t ablk = ((size_t)(gm * 4 + wv_m) * 32) * 256;  // + ks*256 + p*64 + lane

    // --- epilogue constants ---
    const int j = jt * 16 + (lane & 15);
    const int be = m0 + wv_m * 16 + (lane >> 4) * 4;
    float wi_[4], bs_[4];
#pragma unroll
    for (int g = 0; g < 4; ++g) {
        wi_[g] = W_ih[g * HH + j];
        bs_[g] = b_ih[g * HH + j] + b_hh[g * HH + j];
    }
    float c_[4];
#pragma unroll
    for (int r = 0; r < 4; ++r) c_[r] = c0[(size_t)(be + r) * HH + j];
    const int ksj = j >> 5, pj = (j & 7) >> 1, hfj = j & 1;
    const size_t sblk = (((size_t)(gm * 4 + wv_m) * 32 + ksj) * 4 + pj) * 64 +
                        (((j & 31) >> 3) << 4) + ((lane >> 4) << 2);

    // prologue: stage W_lo iter 0 into buf 0 (conflict-free)
#pragma unroll
    for (int p = 0; p < 2; ++p)
        *(short8*)&Wls[0][sloff[p]] = *(const short8*)(WloG + sgoff[p]);
    __syncthreads();

    unsigned int* mycnt = cnt + gm * 32;
    float* scr = (float*)&Wls[1][0];           // 16 KB reduction scratch (reused)

    union U8 { short8 s8; unsigned int u[4]; };

    for (int t = 0; t < TT; ++t) {
        const unsigned long long* hR = hbase + (size_t)(t & 1) * HP_U64;
        unsigned int* hW32 = (unsigned int*)(hbase + (size_t)((t + 1) & 1) * HP_U64);

        float4v acc[4] = {{0.f, 0.f, 0.f, 0.f}, {0.f, 0.f, 0.f, 0.f},
                          {0.f, 0.f, 0.f, 0.f}, {0.f, 0.f, 0.f, 0.f}};
        unsigned long long au_cur[2][4], au_nxt[2][4];

        // A prologue: chunk 0 (plain cached loads; L2 fresh after fence)
#pragma unroll
        for (int ksl = 0; ksl < 2; ++ksl) {
            int ks = wv_k * 16 + ksl;
#pragma unroll
            for (int p = 0; p < 4; ++p)
                au_cur[ksl][p] = hR[ablk + (size_t)ks * 256 + p * 64 + lane];
        }

        for (int i = 0; i < 8; ++i) {
            if (i < 7) {
#pragma unroll
                for (int ksl = 0; ksl < 2; ++ksl) {
                    int ks = wv_k * 16 + (i + 1) * 2 + ksl;
#pragma unroll
                    for (int p = 0; p < 4; ++p)
                        au_nxt[ksl][p] = hR[ablk + (size_t)ks * 256 + p * 64 + lane];
                }
            }
            // stage W_lo iter (i+1)&7 into buf (i+1)&1 (at i=7: iter0 for next step)
            {
                const size_t itoff = (size_t)(((i + 1) & 7) * 2) * 512;
#pragma unroll
                for (int p = 0; p < 2; ++p)
                    *(short8*)&Wls[(i + 1) & 1][sloff[p]] =
                        *(const short8*)(WloG + sgoff[p] + itoff);
            }
            // compute on au_cur + Wls[i&1]
#pragma unroll
            for (int ksl = 0; ksl < 2; ++ksl) {
                const int ks = wv_k * 16 + i * 2 + ksl;
                U8 ah, al;
#pragma unroll
                for (int d = 0; d < 4; ++d) {
                    unsigned int w0 = (unsigned int)au_cur[ksl][d];
                    unsigned int w1 = (unsigned int)(au_cur[ksl][d] >> 32);
                    ah.u[d] = (w0 & 0xFFFFu) | (w1 << 16);
                    al.u[d] = (w0 >> 16) | (w1 & 0xFFFF0000u);
                }
#pragma unroll
                for (int g = 0; g < 4; ++g) {
                    short8 bh = *(const short8*)&Whi[((g * 32 + ks) * 64 + lane) * 8];
                    short8 bl = *(const short8*)
                        &Wls[i & 1][(((wv_k * 4 + g) * 2 + ksl) * 64 + lane) * 8];
                    acc[g] = MFMA(ah.s8, bh, acc[g]);   // A_hi * W_hi
                    acc[g] = MFMA(ah.s8, bl, acc[g]);   // A_hi * W_lo
                    acc[g] = MFMA(al.s8, bh, acc[g]);   // A_lo * W_hi
                }
            }
            __syncthreads();
#pragma unroll
            for (int ksl = 0; ksl < 2; ++ksl)
#pragma unroll
                for (int p = 0; p < 4; ++p) au_cur[ksl][p] = au_nxt[ksl][p];
        }

        // --- cross-wv_k reduction through LDS scratch ---
        if (wv_k == 1) {
            const int tid2 = tid - 256;
#pragma unroll
            for (int g = 0; g < 4; ++g)
                *(float4v*)&scr[(g * 256 + tid2) * 4] = acc[g];
        }
        __syncthreads();

        if (wv_k == 0) {
#pragma unroll
            for (int g = 0; g < 4; ++g) {
                float4v part = *(const float4v*)&scr[(g * 256 + tid) * 4];
                acc[g] += part;
            }
            // --- epilogue: gates -> c,h update; agent-scope h stores ---
#pragma unroll
            for (int r = 0; r < 4; ++r) {
                float x = y_hist[(size_t)(be + r) * TT + t];
                float gi = acc[0][r] + x * wi_[0] + bs_[0];
                float gf = acc[1][r] + x * wi_[1] + bs_[1];
                float gg = acc[2][r] + x * wi_[2] + bs_[2];
                float go = acc[3][r] + x * wi_[3] + bs_[3];
                float cn = sigf(gf) * c_[r] + sigf(gi) * tanhff(gg);
                float hn = sigf(go) * tanhff(cn);
                c_[r] = cn;
                unsigned short hi = f2bf(hn);
                unsigned short lo = f2bf(hn - bf2f(hi));
                unsigned int word = (unsigned int)hi | ((unsigned int)lo << 16);
                __hip_atomic_store(&hW32[(sblk + r) * 2 + hfj], word,
                                   __ATOMIC_RELAXED, __HIP_MEMORY_SCOPE_AGENT);
            }
        }

        // --- m-group barrier; then acquire-agent fence invalidates stale L2 ---
        __syncthreads();   // drains vmcnt(0): h stores are LLC-visible
        if (tid == 0) {
            __hip_atomic_fetch_add(mycnt, 1u, __ATOMIC_RELAXED, __HIP_MEMORY_SCOPE_AGENT);
            unsigned target = 64u * (unsigned)(t + 1);
            while (__hip_atomic_load(mycnt, __ATOMIC_RELAXED, __HIP_MEMORY_SCOPE_AGENT) <
                   target)
                __builtin_amdgcn_s_sleep(1);
        }
        __syncthreads();
        __builtin_amdgcn_fence(__ATOMIC_ACQUIRE, "agent");  // buffer_inv: fresh L2 view
    }

    // --- final FC (h final in buffer 0): jt==0 WGs, wv_k==0 waves ---
    if (jt == 0 && wv_k == 0) {
        const unsigned int* hF32 = (const unsigned int*)hbase;   // buffer 0
#pragma unroll 1
        for (int rr = 0; rr < 16; ++rr) {
            int b = m0 + wv_m * 16 + rr;
            float s = 0.f;
#pragma unroll 1
            for (int ii = 0; ii < 16; ++ii) {
                int k = ii * 64 + lane;
                int l = (rr & 15) + (((k & 31) >> 3) << 4);
                size_t idx64 = (((size_t)(gm * 4 + wv_m) * 32 + (k >> 5)) * 4 +
                                ((k & 7) >> 1)) * 64 + l;
                unsigned int word = hF32[idx64 * 2 + (k & 1)];
                float hv = bf2f((unsigned short)(word & 0xFFFFu)) +
                           bf2f((unsigned short)(word >> 16));
                s = fmaf(hv, W_fc[k], s);
            }
#pragma unroll
            for (int off = 32; off > 0; off >>= 1) s += __shfl_xor(s, off);
            if (lane == 0) out[b] = s + b_fc[0];
        }
    }
}

extern "C" void kernel_launch(void* const* d_in, const int* in_sizes, int n_in,
                              void* d_out, int out_size, void* d_ws, size_t ws_size,
                              hipStream_t stream) {
    const float* y_hist = (const float*)d_in[0];
    const float* W_ih   = (const float*)d_in[1];
    const float* W_hh   = (const float*)d_in[2];
    const float* b_ih   = (const float*)d_in[3];
    const float* b_hh   = (const float*)d_in[4];
    const float* W_fc   = (const float*)d_in[5];
    const float* b_fc   = (const float*)d_in[6];
    const float* h0     = (const float*)d_in[7];
    const float* c0     = (const float*)d_in[8];
    float* out = (float*)d_out;

    // ws: Wp hi/lo (16 MB) | h buffers 2 x 1 MB | cnt (512 B)
    unsigned short* Wp = (unsigned short*)d_ws;
    unsigned long long* hbase = (unsigned long long*)(Wp + 2 * WP_CPOFF);
    unsigned int* cnt = (unsigned int*)(hbase + 2 * HP_U64);

    pack_w<<<2048, 256, 0, stream>>>(W_hh, Wp);
    prep_state<<<1024, 256, 0, stream>>>(h0, (unsigned int*)hbase, cnt);

    // 256 WGs x 512 threads, 160 KiB LDS -> 1 WG/CU, all co-resident
    lstm_persist<<<256, 512, 0, stream>>>(y_hist, W_ih, b_ih, b_hh, c0, W_fc, b_fc,
                                          Wp, hbase, cnt, out);
}

// Round 6
// 5210.270 us; speedup vs baseline: 2.3901x; 2.3901x over previous
//
#include <hip/hip_runtime.h>
#include <hip/hip_bf16.h>

// LSTM decoder B=256, T=512, H=1024 — persistent split-bf16 MFMA, v4.
// = R4 (proven 5.5ms) + R5's conflict-free W_lo staging (proven conflicts->0)
// + coalesced full-line h stores:
//   epilogue threads own (2 rows x 2 adjacent j) cells -> one 16B dwordx4
//   store with sc0 sc1 (LLC-visible, per-instruction line coalescing, no
//   sector RMW at the memory-side cache). Gate tile re-partitioned via a
//   16KB XOR-swizzled LDS scratch round-trip.
// A loads remain agent-scope relaxed u64 atomics (bypass L1/L2, hit LLC).

#define BB 256
#define TT 512
#define HH 1024

typedef __attribute__((ext_vector_type(8))) short short8;
typedef __attribute__((ext_vector_type(4))) float float4v;
typedef __attribute__((ext_vector_type(2))) float float2v;
typedef __attribute__((ext_vector_type(4))) unsigned int uint4v;

#define MFMA(a, b, c) __builtin_amdgcn_mfma_f32_16x16x32_bf16((a), (b), (c), 0, 0, 0)

#define WP_CPOFF ((size_t)4194304)   // shorts per W plane: 64jt*4g*32ks*64lane*8
#define HP_U64   ((size_t)131072)    // u64 per h buffer: 16blk*32ks*4p*64lane

__device__ __forceinline__ float sigf(float x) { return 1.0f / (1.0f + __expf(-x)); }
__device__ __forceinline__ float tanhff(float x) {
    return 1.0f - 2.0f / (__expf(2.0f * x) + 1.0f);
}
__device__ __forceinline__ unsigned short f2bf(float x) {
    __hip_bfloat16 b = __float2bfloat16(x);
    return __builtin_bit_cast(unsigned short, b);
}
__device__ __forceinline__ float bf2f(unsigned short u) {
    __hip_bfloat16 b = __builtin_bit_cast(__hip_bfloat16, u);
    return __bfloat162float(b);
}
__device__ __forceinline__ void store_u128_llc(void* p, uint4v v) {
    // plain dwordx4 write-through past L1/L2 -> visible at LLC, line-coalesced
    asm volatile("global_store_dwordx4 %0, %1, off sc0 sc1" : : "v"(p), "v"(v) : "memory");
}

// ---- pack W_hh (4096x1024 f32) into fragment-ordered bf16 hi/lo planes ----
__global__ __launch_bounds__(256) void pack_w(const float* __restrict__ W_hh,
                                              unsigned short* __restrict__ Wp) {
    int gid = blockIdx.x * 256 + threadIdx.x;   // 0..524287
    int lane = gid & 63;
    int ks = (gid >> 6) & 31;
    int g = (gid >> 11) & 3;
    int jt = (gid >> 13) & 63;
    int r = g * HH + jt * 16 + (lane & 15);
    int k = ks * 32 + (lane >> 4) * 8;
    const float* src = W_hh + (size_t)r * HH + k;
    size_t base = ((((size_t)jt * 4 + g) * 32 + ks) * 64 + lane) * 8;
#pragma unroll
    for (int e = 0; e < 8; ++e) {
        float v = src[e];
        unsigned short hi = f2bf(v);
        Wp[base + e] = hi;
        Wp[WP_CPOFF + base + e] = f2bf(v - bf2f(hi));
    }
}

// ---- h0 -> packed fragment layout in buffer 0; zero barrier counters ----
__global__ __launch_bounds__(256) void prep_state(const float* __restrict__ h0,
                                                  unsigned int* __restrict__ hb0,
                                                  unsigned int* __restrict__ cnt) {
    int gid = blockIdx.x * 256 + threadIdx.x;   // 0..262143
    int r = gid >> 10, k = gid & 1023;
    float v = h0[gid];
    unsigned short hi = f2bf(v);
    unsigned short lo = f2bf(v - bf2f(hi));
    unsigned int word = (unsigned int)hi | ((unsigned int)lo << 16);
    int blk = ((r >> 6) << 2) | ((r >> 4) & 3);
    int l = (r & 15) + (((k & 31) >> 3) << 4);
    size_t idx64 = (((size_t)blk * 32 + (k >> 5)) * 4 + ((k & 7) >> 1)) * 64 + l;
    hb0[idx64 * 2 + (k & 1)] = word;
    if (blockIdx.x == 0 && threadIdx.x < 128) cnt[threadIdx.x] = 0;
}

// ---- persistent LSTM kernel: all 512 steps + final FC ----
__global__ __launch_bounds__(512, 1) void lstm_persist(
    const float* __restrict__ y_hist,
    const float* __restrict__ W_ih,           // (4096) flat
    const float* __restrict__ b_ih,
    const float* __restrict__ b_hh,
    const float* __restrict__ c0,             // (B,H) f32
    const float* __restrict__ W_fc,           // (H)
    const float* __restrict__ b_fc,           // (1)
    const unsigned short* __restrict__ Wp,    // packed hi/lo planes
    unsigned long long* hbase,                // 2 buffers x HP_U64 u64
    unsigned int* cnt,
    float* __restrict__ out)
{
    __shared__ unsigned short Whi[65536];      // 128 KB persistent W_hi slice
    __shared__ __align__(16) unsigned short Wls[2][8192];  // 2 x 16 KB W_lo dbuf
    // 160 KiB exactly -> 1 WG/CU, grid=256 => all WGs co-resident

    const int tid = threadIdx.x;
    const int lane = tid & 63;
    const int wv = tid >> 6;
    const int wv_m = wv & 3;                   // m-subtile (16 rows)
    const int wv_k = wv >> 2;                  // K half
    const int bid = blockIdx.x;
    const int jt = ((bid & 7) << 3) | ((bid >> 3) & 7);  // XCD-swizzled j-tile
    const int gm = bid >> 6;                   // m-group 0..3
    const int m0 = gm << 6;

    // --- persistent W_hi slice -> LDS (coalesced b128) ---
    const unsigned short* WhiG = Wp + (size_t)jt * 65536;
    for (int i = tid; i < 8192; i += 512)
        *(short8*)&Whi[(size_t)i * 8] = *(const short8*)(WhiG + (size_t)i * 8);

    // --- W_lo staging: wave wv stages fragments {2wv, 2wv+1}, 16 B/lane (CF) ---
    const unsigned short* WloG = Wp + WP_CPOFF + (size_t)jt * 65536;
    size_t sgoff[2];
    int sloff[2];
#pragma unroll
    for (int p = 0; p < 2; ++p) {
        int fi = wv * 2 + p;   // = swk*8 + sg*2 + sksl
        sgoff[p] = (size_t)((((fi >> 1) & 3) * 32 + (fi >> 3) * 16 + (fi & 1)) * 512) + lane * 8;
        sloff[p] = fi * 512 + lane * 8;
    }

    // --- A addressing: u64 block base for (gm, wv_m) ---
    const size_t ablk = ((size_t)(gm * 4 + wv_m) * 32) * 256;  // + ks*256 + p*64 + lane

    // --- epilogue constants (wv_k==0 threads: cell = 2 rows x 2 adjacent j) ---
    const int m2 = lane & 7;                   // row-pair index
    const int jjl = lane >> 3;                 // j-pair index 0..7
    const int mrow = wv_m * 16 + m2 * 2;       // tile-local rows mrow, mrow+1
    const int bm = m0 + mrow;                  // global batch rows bm, bm+1
    const int ksj = jt >> 1;
    const int pj = jjl & 3;
    const int qj = 2 * (jt & 1) + (jjl >> 2);
    const size_t sbase = ((size_t)(gm * 4 + wv_m) * 32 + ksj) * 256 +
                         pj * 64 + qj * 16 + m2 * 2;   // u64 index of row-pair
    float wi_[4][2], bs_[4][2];
    float c_[2][2];                            // [rr][h]
    if (wv_k == 0) {
#pragma unroll
        for (int g = 0; g < 4; ++g)
#pragma unroll
            for (int h = 0; h < 2; ++h) {
                int j = jt * 16 + 2 * jjl + h;
                wi_[g][h] = W_ih[g * HH + j];
                bs_[g][h] = b_ih[g * HH + j] + b_hh[g * HH + j];
            }
#pragma unroll
        for (int rr = 0; rr < 2; ++rr)
#pragma unroll
            for (int h = 0; h < 2; ++h)
                c_[rr][h] = c0[(size_t)(bm + rr) * HH + jt * 16 + 2 * jjl + h];
    }

    // prologue: stage W_lo iter 0 into buf 0 (conflict-free)
#pragma unroll
    for (int p = 0; p < 2; ++p)
        *(short8*)&Wls[0][sloff[p]] = *(const short8*)(WloG + sgoff[p]);
    __syncthreads();

    unsigned int* mycnt = cnt + gm * 32;
    float* scr = (float*)&Wls[1][0];           // 16 KB = [64 n][64 m-swizzled] f32

    union U8 { short8 s8; unsigned int u[4]; };

    for (int t = 0; t < TT; ++t) {
        const unsigned long long* hR = hbase + (size_t)(t & 1) * HP_U64;
        unsigned long long* hW = hbase + (size_t)((t + 1) & 1) * HP_U64;

        float4v acc[4] = {{0.f, 0.f, 0.f, 0.f}, {0.f, 0.f, 0.f, 0.f},
                          {0.f, 0.f, 0.f, 0.f}, {0.f, 0.f, 0.f, 0.f}};
        unsigned long long au_cur[2][4], au_nxt[2][4];

        // A prologue: chunk 0 (agent-scope relaxed u64: bypass L1/L2, read LLC)
#pragma unroll
        for (int ksl = 0; ksl < 2; ++ksl) {
            int ks = wv_k * 16 + ksl;
#pragma unroll
            for (int p = 0; p < 4; ++p)
                au_cur[ksl][p] = __hip_atomic_load(
                    (unsigned long long*)&hR[ablk + (size_t)ks * 256 + p * 64 + lane],
                    __ATOMIC_RELAXED, __HIP_MEMORY_SCOPE_AGENT);
        }

        for (int i = 0; i < 8; ++i) {
            if (i < 7) {
#pragma unroll
                for (int ksl = 0; ksl < 2; ++ksl) {
                    int ks = wv_k * 16 + (i + 1) * 2 + ksl;
#pragma unroll
                    for (int p = 0; p < 4; ++p)
                        au_nxt[ksl][p] = __hip_atomic_load(
                            (unsigned long long*)&hR[ablk + (size_t)ks * 256 + p * 64 + lane],
                            __ATOMIC_RELAXED, __HIP_MEMORY_SCOPE_AGENT);
                }
            }
            // stage W_lo iter (i+1)&7 into buf (i+1)&1 (at i=7: iter0 for next step)
            {
                const size_t itoff = (size_t)(((i + 1) & 7) * 2) * 512;
#pragma unroll
                for (int p = 0; p < 2; ++p)
                    *(short8*)&Wls[(i + 1) & 1][sloff[p]] =
                        *(const short8*)(WloG + sgoff[p] + itoff);
            }
            // compute on au_cur + Wls[i&1]
#pragma unroll
            for (int ksl = 0; ksl < 2; ++ksl) {
                const int ks = wv_k * 16 + i * 2 + ksl;
                U8 ah, al;
#pragma unroll
                for (int d = 0; d < 4; ++d) {
                    unsigned int w0 = (unsigned int)au_cur[ksl][d];
                    unsigned int w1 = (unsigned int)(au_cur[ksl][d] >> 32);
                    ah.u[d] = (w0 & 0xFFFFu) | (w1 << 16);
                    al.u[d] = (w0 >> 16) | (w1 & 0xFFFF0000u);
                }
#pragma unroll
                for (int g = 0; g < 4; ++g) {
                    short8 bh = *(const short8*)&Whi[((g * 32 + ks) * 64 + lane) * 8];
                    short8 bl = *(const short8*)
                        &Wls[i & 1][(((wv_k * 4 + g) * 2 + ksl) * 64 + lane) * 8];
                    acc[g] = MFMA(ah.s8, bh, acc[g]);   // A_hi * W_hi
                    acc[g] = MFMA(ah.s8, bl, acc[g]);   // A_hi * W_lo
                    acc[g] = MFMA(al.s8, bh, acc[g]);   // A_lo * W_hi
                }
            }
            __syncthreads();
#pragma unroll
            for (int ksl = 0; ksl < 2; ++ksl)
#pragma unroll
                for (int p = 0; p < 4; ++p) au_cur[ksl][p] = au_nxt[ksl][p];
        }

        // --- reduction via XOR-swizzled scratch: scr[n][m ^ ((n&7)<<3)] ---
        if (wv_k == 1) {
#pragma unroll
            for (int g = 0; g < 4; ++g) {
                int n = g * 16 + (lane & 15);
                int mb = (wv_m * 16 + (lane >> 4) * 4) ^ ((n & 7) << 3);
                *(float4v*)&scr[n * 64 + mb] = acc[g];
            }
        }
        __syncthreads();
        if (wv_k == 0) {
#pragma unroll
            for (int g = 0; g < 4; ++g) {
                int n = g * 16 + (lane & 15);
                int mb = (wv_m * 16 + (lane >> 4) * 4) ^ ((n & 7) << 3);
                float4v part = *(const float4v*)&scr[n * 64 + mb];
                acc[g] += part;
                *(float4v*)&scr[n * 64 + mb] = acc[g];   // final G back to scr
            }
        }
        __syncthreads();

        // --- epilogue (wv_k==0): cell = rows (bm,bm+1) x j-pair; 16B LLC store ---
        if (wv_k == 0) {
            float G[4][2][2];   // [g][h][rr]
#pragma unroll
            for (int g = 0; g < 4; ++g)
#pragma unroll
                for (int h = 0; h < 2; ++h) {
                    int n = g * 16 + 2 * jjl + h;
                    float2v gp = *(const float2v*)&scr[n * 64 + (mrow ^ ((n & 7) << 3))];
                    G[g][h][0] = gp.x;
                    G[g][h][1] = gp.y;
                }
            unsigned int w[2][2];   // [rr][h]
#pragma unroll
            for (int rr = 0; rr < 2; ++rr) {
                float x = y_hist[(size_t)(bm + rr) * TT + t];
#pragma unroll
                for (int h = 0; h < 2; ++h) {
                    float gi = G[0][h][rr] + x * wi_[0][h] + bs_[0][h];
                    float gf = G[1][h][rr] + x * wi_[1][h] + bs_[1][h];
                    float gg = G[2][h][rr] + x * wi_[2][h] + bs_[2][h];
                    float go = G[3][h][rr] + x * wi_[3][h] + bs_[3][h];
                    float cn = sigf(gf) * c_[rr][h] + sigf(gi) * tanhff(gg);
                    float hn = sigf(go) * tanhff(cn);
                    c_[rr][h] = cn;
                    unsigned short hi = f2bf(hn);
                    unsigned short lo = f2bf(hn - bf2f(hi));
                    w[rr][h] = (unsigned int)hi | ((unsigned int)lo << 16);
                }
            }
            uint4v data;
            data.x = w[0][0]; data.y = w[0][1];   // u64 for row bm
            data.z = w[1][0]; data.w = w[1][1];   // u64 for row bm+1
            store_u128_llc((void*)(hW + sbase), data);
        }

        // --- drain asm stores, then m-group barrier ---
        asm volatile("s_waitcnt vmcnt(0)" ::: "memory");
        __syncthreads();
        if (tid == 0) {
            __hip_atomic_fetch_add(mycnt, 1u, __ATOMIC_RELAXED, __HIP_MEMORY_SCOPE_AGENT);
            unsigned target = 64u * (unsigned)(t + 1);
            while (__hip_atomic_load(mycnt, __ATOMIC_RELAXED, __HIP_MEMORY_SCOPE_AGENT) <
                   target)
                __builtin_amdgcn_s_sleep(1);
        }
        __syncthreads();
    }

    // --- final FC (h final in buffer 0): jt==0 WGs, wv_k==0 waves ---
    if (jt == 0 && wv_k == 0) {
        const unsigned int* hF32 = (const unsigned int*)hbase;   // buffer 0
#pragma unroll 1
        for (int rr = 0; rr < 16; ++rr) {
            int b = m0 + wv_m * 16 + rr;
            float s = 0.f;
#pragma unroll 1
            for (int ii = 0; ii < 16; ++ii) {
                int k = ii * 64 + lane;
                int l = (rr & 15) + (((k & 31) >> 3) << 4);
                size_t idx64 = (((size_t)(gm * 4 + wv_m) * 32 + (k >> 5)) * 4 +
                                ((k & 7) >> 1)) * 64 + l;
                unsigned int word = hF32[idx64 * 2 + (k & 1)];
                float hv = bf2f((unsigned short)(word & 0xFFFFu)) +
                           bf2f((unsigned short)(word >> 16));
                s = fmaf(hv, W_fc[k], s);
            }
#pragma unroll
            for (int off = 32; off > 0; off >>= 1) s += __shfl_xor(s, off);
            if (lane == 0) out[b] = s + b_fc[0];
        }
    }
}

extern "C" void kernel_launch(void* const* d_in, const int* in_sizes, int n_in,
                              void* d_out, int out_size, void* d_ws, size_t ws_size,
                              hipStream_t stream) {
    const float* y_hist = (const float*)d_in[0];
    const float* W_ih   = (const float*)d_in[1];
    const float* W_hh   = (const float*)d_in[2];
    const float* b_ih   = (const float*)d_in[3];
    const float* b_hh   = (const float*)d_in[4];
    const float* W_fc   = (const float*)d_in[5];
    const float* b_fc   = (const float*)d_in[6];
    const float* h0     = (const float*)d_in[7];
    const float* c0     = (const float*)d_in[8];
    float* out = (float*)d_out;

    // ws: Wp hi/lo (16 MB) | h buffers 2 x 1 MB | cnt (512 B)
    unsigned short* Wp = (unsigned short*)d_ws;
    unsigned long long* hbase = (unsigned long long*)(Wp + 2 * WP_CPOFF);
    unsigned int* cnt = (unsigned int*)(hbase + 2 * HP_U64);

    pack_w<<<2048, 256, 0, stream>>>(W_hh, Wp);
    prep_state<<<1024, 256, 0, stream>>>(h0, (unsigned int*)hbase, cnt);

    // 256 WGs x 512 threads, 160 KiB LDS -> 1 WG/CU, all co-resident
    lstm_persist<<<256, 512, 0, stream>>>(y_hist, W_ih, b_ih, b_hh, c0, W_fc, b_fc,
                                          Wp, hbase, cnt, out);
}

// Round 7
// 2942.014 us; speedup vs baseline: 4.2329x; 1.7710x over previous
//
#include <hip/hip_runtime.h>
#include <hip/hip_bf16.h>

// LSTM decoder B=256, T=512, H=1024 — persistent fp16 MFMA, v5.
// Diagnosis R6: A-path LLC reads (64 MB/step) at ~6.3 TB/s are the wall.
// v5: full fp16 1-term GEMM (h and W_hh in fp16; err ~2^-11, threshold 7.5e-4):
//   * A traffic halved: 32 MB/step (fp16 single plane, fragment-packed).
//   * W slice (64n x 1024k fp16 = 128 KB) fully persistent in LDS ->
//     NO W_lo streaming, NO syncthreads inside the K-loop (sync-free).
//   * A loads: agent-scope u64 atomics (R4/R6-proven), 4-deep prefetch ring.
//   * h stores: lane-coalesced 8B dwordx2 sc0 sc1 (R6-proven, no sector RMW).
//   * MFMA 16x16x32_f16 (m89-verified layout family); waves = 4m x 2k.

#define BB 256
#define TT 512
#define HH 1024

typedef __attribute__((ext_vector_type(8))) short short8;
typedef __attribute__((ext_vector_type(8))) _Float16 half8;
typedef __attribute__((ext_vector_type(4))) float float4v;

#define HP_U64 ((size_t)65536)   // u64 per h buffer: 256 U-units x 256 rows

__device__ __forceinline__ float sigf(float x) { return 1.0f / (1.0f + __expf(-x)); }
__device__ __forceinline__ float tanhff(float x) {
    return 1.0f - 2.0f / (__expf(2.0f * x) + 1.0f);
}

// h fragment-packed fp16 layout. Element (row M, col k):
//   U = (k>>5)*8 + ((k>>2)&7)  with k = kc*32 + q*8 + eh*4 + e2
//   u64 unit index = U*256 + (M>>4)*16 + (M&15); e2 = k&3 selects fp16 in unit.

// ---- pack W_hh (4096x1024 f32) -> fp16 fragment order, contiguous per jt ----
// Wp[jt][ks(32)][g(4)][lane(64)][8] fp16 ; per-jt block = 128 KB
__global__ __launch_bounds__(256) void pack_w(const float* __restrict__ W_hh,
                                              unsigned short* __restrict__ Wp) {
    int f = blockIdx.x * 256 + threadIdx.x;   // 0..524287
    int l = f & 63;
    int g = (f >> 6) & 3;
    int ks = (f >> 8) & 31;
    int jt = f >> 13;
    int r = g * HH + jt * 16 + (l & 15);
    int k = ks * 32 + (l >> 4) * 8;
    const float* src = W_hh + (size_t)r * HH + k;
    union { _Float16 h[8]; short8 s; } u;
#pragma unroll
    for (int e = 0; e < 8; ++e) u.h[e] = (_Float16)src[e];
    *(short8*)(Wp + (size_t)f * 8) = u.s;
}

// ---- h0 -> fp16 fragment layout in buffer 0; zero barrier counters ----
__global__ __launch_bounds__(256) void prep_state(const float* __restrict__ h0,
                                                  unsigned long long* __restrict__ hb0,
                                                  unsigned int* __restrict__ cnt) {
    int gid = blockIdx.x * 256 + threadIdx.x;   // 0..65535
    int r = gid & 255;
    int U = gid >> 8;
    int kb = (U >> 3) * 32 + ((U >> 1) & 3) * 8 + (U & 1) * 4;
    float4 v = *(const float4*)(h0 + (size_t)r * HH + kb);
    union { _Float16 h[4]; unsigned long long u; } x;
    x.h[0] = (_Float16)v.x; x.h[1] = (_Float16)v.y;
    x.h[2] = (_Float16)v.z; x.h[3] = (_Float16)v.w;
    hb0[(size_t)U * 256 + r] = x.u;
    if (blockIdx.x == 0 && threadIdx.x < 128) cnt[threadIdx.x] = 0;
}

// ---- persistent LSTM kernel: all 512 steps + final FC ----
__global__ __launch_bounds__(512, 1) void lstm_persist(
    const float* __restrict__ y_hist,
    const float* __restrict__ W_ih,           // (4096) flat
    const float* __restrict__ b_ih,
    const float* __restrict__ b_hh,
    const float* __restrict__ c0,             // (B,H) f32
    const float* __restrict__ W_fc,           // (H)
    const float* __restrict__ b_fc,           // (1)
    const unsigned short* __restrict__ Wp,    // packed fp16 W
    unsigned long long* hbase,                // 2 buffers x HP_U64 u64
    unsigned int* cnt,
    float* __restrict__ out)
{
    __shared__ __align__(16) unsigned short Wlds[65536];   // 128 KB fp16 W slice
    __shared__ __align__(16) float scr[4096];              // 16 KB reduce/regroup
    // 144 KB LDS -> 1 WG/CU; grid=256 => all WGs co-resident

    const int tid = threadIdx.x;
    const int lane = tid & 63;
    const int wv = tid >> 6;
    const int wv_m = wv & 3;                   // m-subtile (16 rows)
    const int wv_k = wv >> 2;                  // K half
    const int bid = blockIdx.x;
    const int jt = ((bid & 7) << 3) | ((bid >> 3) & 7);  // XCD-swizzled j-tile
    const int gm = bid >> 6;                   // m-group 0..3
    const int m0 = gm << 6;

    // --- persistent fp16 W slice -> LDS (coalesced b128, conflict-free) ---
    const unsigned short* WG_ = Wp + (size_t)jt * 65536;
    for (int i = tid; i < 8192; i += 512)
        *(short8*)&Wlds[(size_t)i * 8] = *(const short8*)(WG_ + (size_t)i * 8);

    // --- A addressing: wave covers rows blk*16.., lanes (m4 = lane&15, q = lane>>4)
    const int blk = gm * 4 + wv_m;
    const size_t ubase = (size_t)(lane >> 4) * 512 + blk * 16 + (lane & 15);

    // --- epilogue constants (k0 threads, tid<256): cell = 1 row x 4 j ---
    const int em = tid & 63;                   // tile-local row
    const int jq = (tid >> 6) & 3;             // j-quad
    const int M = m0 + em;                     // global batch row
    float wi_[4][4], bs_[4][4];                // [g][jj]
    float c_[4];
    if (wv_k == 0) {
#pragma unroll
        for (int g = 0; g < 4; ++g)
#pragma unroll
            for (int jj = 0; jj < 4; ++jj) {
                int j = jt * 16 + jq * 4 + jj;
                wi_[g][jj] = W_ih[g * HH + j];
                bs_[g][jj] = b_ih[g * HH + j] + b_hh[g * HH + j];
            }
#pragma unroll
        for (int jj = 0; jj < 4; ++jj)
            c_[jj] = c0[(size_t)M * HH + jt * 16 + jq * 4 + jj];
    }
    // h-store unit for this thread's cell
    const size_t sunit = (size_t)(jt >> 1) * 2048 + ((jt & 1) * 4 + jq) * 256 +
                         (gm * 4 + (em >> 4)) * 16 + (em & 15);

    __syncthreads();   // Wlds visible

    unsigned int* mycnt = cnt + gm * 32;

    for (int t = 0; t < TT; ++t) {
        const unsigned long long* hR = hbase + (size_t)(t & 1) * HP_U64;
        unsigned long long* hW = hbase + (size_t)((t + 1) & 1) * HP_U64;

        float4v acc[4] = {{0.f, 0.f, 0.f, 0.f}, {0.f, 0.f, 0.f, 0.f},
                          {0.f, 0.f, 0.f, 0.f}, {0.f, 0.f, 0.f, 0.f}};

        // --- sync-free K-loop: 16 chunks of K=32, 4-deep A prefetch ring ---
        unsigned long long aB[4][2];
#pragma unroll
        for (int p = 0; p < 4; ++p) {
            size_t ua = (size_t)(wv_k * 16 + p) * 2048 + ubase;
            aB[p][0] = __hip_atomic_load((unsigned long long*)&hR[ua],
                                         __ATOMIC_RELAXED, __HIP_MEMORY_SCOPE_AGENT);
            aB[p][1] = __hip_atomic_load((unsigned long long*)&hR[ua + 256],
                                         __ATOMIC_RELAXED, __HIP_MEMORY_SCOPE_AGENT);
        }
#pragma unroll
        for (int ch = 0; ch < 16; ++ch) {
            union { unsigned long long u[2]; half8 h; } af;
            af.u[0] = aB[ch & 3][0];
            af.u[1] = aB[ch & 3][1];
            if (ch < 12) {
                size_t ua = (size_t)(wv_k * 16 + ch + 4) * 2048 + ubase;
                aB[ch & 3][0] = __hip_atomic_load((unsigned long long*)&hR[ua],
                                                  __ATOMIC_RELAXED, __HIP_MEMORY_SCOPE_AGENT);
                aB[ch & 3][1] = __hip_atomic_load((unsigned long long*)&hR[ua + 256],
                                                  __ATOMIC_RELAXED, __HIP_MEMORY_SCOPE_AGENT);
            }
            const int ks = wv_k * 16 + ch;
#pragma unroll
            for (int g = 0; g < 4; ++g) {
                half8 bh = *(const half8*)&Wlds[((ks * 4 + g) * 64 + lane) * 8];
                acc[g] = __builtin_amdgcn_mfma_f32_16x16x32_f16(af.h, bh, acc[g], 0, 0, 0);
            }
        }

        // --- reduction: wv_k==1 partials -> swizzled scratch; k0 adds ---
        if (wv_k == 1) {
#pragma unroll
            for (int g = 0; g < 4; ++g) {
                int n = g * 16 + (lane & 15);
                int mb = (wv_m * 16 + (lane >> 4) * 4) ^ ((n & 7) << 3);
                *(float4v*)&scr[n * 64 + mb] = acc[g];
            }
        }
        __syncthreads();
        if (wv_k == 0) {
#pragma unroll
            for (int g = 0; g < 4; ++g) {
                int n = g * 16 + (lane & 15);
                int mb = (wv_m * 16 + (lane >> 4) * 4) ^ ((n & 7) << 3);
                float4v part = *(const float4v*)&scr[n * 64 + mb];
                acc[g] += part;
                *(float4v*)&scr[n * 64 + mb] = acc[g];   // final G back to scr
            }
        }
        __syncthreads();

        // --- epilogue (k0 threads): 1 row x 4 j cell, one u64 sc0sc1 store ---
        if (wv_k == 0) {
            float x = y_hist[(size_t)M * TT + t];
            union { _Float16 h[4]; unsigned long long u; } hv;
#pragma unroll
            for (int jj = 0; jj < 4; ++jj) {
                int n0 = jq * 4 + jj;
                int msw = em ^ ((n0 & 7) << 3);   // same swizzle for all g (n&7 == n0&7)
                float gi = scr[(0 * 16 + n0) * 64 + msw] + x * wi_[0][jj] + bs_[0][jj];
                float gf = scr[(1 * 16 + n0) * 64 + msw] + x * wi_[1][jj] + bs_[1][jj];
                float gg = scr[(2 * 16 + n0) * 64 + msw] + x * wi_[2][jj] + bs_[2][jj];
                float go = scr[(3 * 16 + n0) * 64 + msw] + x * wi_[3][jj] + bs_[3][jj];
                float cn = sigf(gf) * c_[jj] + sigf(gi) * tanhff(gg);
                float hn = sigf(go) * tanhff(cn);
                c_[jj] = cn;
                hv.h[jj] = (_Float16)hn;
            }
            asm volatile("global_store_dwordx2 %0, %1, off sc0 sc1"
                         : : "v"((void*)(hW + sunit)), "v"(hv.u) : "memory");
        }

        // --- drain stores, then m-group barrier (64 WGs, agent counters) ---
        asm volatile("s_waitcnt vmcnt(0)" ::: "memory");
        __syncthreads();
        if (tid == 0) {
            __hip_atomic_fetch_add(mycnt, 1u, __ATOMIC_RELAXED, __HIP_MEMORY_SCOPE_AGENT);
            unsigned target = 64u * (unsigned)(t + 1);
            while (__hip_atomic_load(mycnt, __ATOMIC_RELAXED, __HIP_MEMORY_SCOPE_AGENT) <
                   target)
                __builtin_amdgcn_s_sleep(1);
        }
        __syncthreads();
    }

    // --- final FC (h final in buffer 0): jt==0 WGs, k0 waves ---
    if (jt == 0 && wv_k == 0) {
        const unsigned long long* hF = hbase;   // buffer 0
#pragma unroll 1
        for (int rr = 0; rr < 16; ++rr) {
            int row = m0 + wv_m * 16 + rr;
            int boff = (row >> 4) * 16 + (row & 15);
            float s = 0.f;
#pragma unroll 1
            for (int uu = 0; uu < 4; ++uu) {
                int U = uu * 64 + lane;
                unsigned long long u = __hip_atomic_load(
                    (unsigned long long*)&hF[(size_t)U * 256 + boff],
                    __ATOMIC_RELAXED, __HIP_MEMORY_SCOPE_AGENT);
                int kb = (U >> 3) * 32 + ((U >> 1) & 3) * 8 + (U & 1) * 4;
                union { _Float16 h[4]; unsigned long long x; } v;
                v.x = u;
                float4 wf = *(const float4*)(W_fc + kb);
                s += (float)v.h[0] * wf.x + (float)v.h[1] * wf.y +
                     (float)v.h[2] * wf.z + (float)v.h[3] * wf.w;
            }
#pragma unroll
            for (int off = 32; off > 0; off >>= 1) s += __shfl_xor(s, off);
            if (lane == 0) out[row] = s + b_fc[0];
        }
    }
}

extern "C" void kernel_launch(void* const* d_in, const int* in_sizes, int n_in,
                              void* d_out, int out_size, void* d_ws, size_t ws_size,
                              hipStream_t stream) {
    const float* y_hist = (const float*)d_in[0];
    const float* W_ih   = (const float*)d_in[1];
    const float* W_hh   = (const float*)d_in[2];
    const float* b_ih   = (const float*)d_in[3];
    const float* b_hh   = (const float*)d_in[4];
    const float* W_fc   = (const float*)d_in[5];
    const float* b_fc   = (const float*)d_in[6];
    const float* h0     = (const float*)d_in[7];
    const float* c0     = (const float*)d_in[8];
    float* out = (float*)d_out;

    // ws: Wp fp16 (8 MB) | h buffers 2 x 512 KB | cnt (512 B)
    unsigned short* Wp = (unsigned short*)d_ws;
    unsigned long long* hbase = (unsigned long long*)(Wp + (size_t)4194304);
    unsigned int* cnt = (unsigned int*)(hbase + 2 * HP_U64);

    pack_w<<<2048, 256, 0, stream>>>(W_hh, Wp);
    prep_state<<<256, 256, 0, stream>>>(h0, hbase, cnt);

    // 256 WGs x 512 threads, 144 KB LDS -> 1 WG/CU, all co-resident
    lstm_persist<<<256, 512, 0, stream>>>(y_hist, W_ih, b_ih, b_hh, c0, W_fc, b_fc,
                                          Wp, hbase, cnt, out);
}

// Round 8
// 2644.770 us; speedup vs baseline: 4.7086x; 1.1124x over previous
//
#include <hip/hip_runtime.h>
#include <hip/hip_bf16.h>

// LSTM decoder B=256, T=512, H=1024 — persistent fp16 MFMA, v6.
// R7 diagnosis: A-path LLC reads (32 MB/step) at fabric ceiling are the wall.
// v6: N_wg=128 (32 j x 4 gates), M_wg=32 -> A traffic halved to 16 MB/step.
//   W slice 256 KB: gates 0,1 (128 KB) persistent in LDS; gates 2,3 held in
//   VGPRs per wave (own K-quarter only: 32 frags = 128 VGPRs).
//   Waves = 2m x 4k; 4-way k-reduction in 2 LDS rounds (32 KB scratch).
//   Barrier: 8 independent m-groups x 32 WGs (agent-scope counters).
//   h layout / agent-atomic A loads / sc0sc1 h stores / FC: unchanged from v5.

#define BB 256
#define TT 512
#define HH 1024

typedef __attribute__((ext_vector_type(8))) short short8;
typedef __attribute__((ext_vector_type(8))) _Float16 half8;
typedef __attribute__((ext_vector_type(4))) float float4v;

#define HP_U64 ((size_t)65536)   // u64 per h buffer: 256 U-units x 256 rows

__device__ __forceinline__ float sigf(float x) { return 1.0f / (1.0f + __expf(-x)); }
__device__ __forceinline__ float tanhff(float x) {
    return 1.0f - 2.0f / (__expf(2.0f * x) + 1.0f);
}

// ---- pack W_hh (4096x1024 f32) -> fp16 B-fragment order ----
// Wp[jt2(32)][kc(32)][g(4)][nt(2)][lane(64)][8] ; per-jt2 block = 256 KB
__global__ __launch_bounds__(256) void pack_w(const float* __restrict__ W_hh,
                                              unsigned short* __restrict__ Wp) {
    int fid = blockIdx.x * 256 + threadIdx.x;   // 0..524287
    int lane = fid & 63;
    int nt = (fid >> 6) & 1;
    int g = (fid >> 7) & 3;
    int kc = (fid >> 9) & 31;
    int jt2 = fid >> 14;
    int j = jt2 * 32 + nt * 16 + (lane & 15);
    int row = g * HH + j;
    int k = kc * 32 + (lane >> 4) * 8;
    const float* src = W_hh + (size_t)row * HH + k;
    union { _Float16 h[8]; short8 s; } u;
#pragma unroll
    for (int e = 0; e < 8; ++e) u.h[e] = (_Float16)src[e];
    *(short8*)(Wp + (size_t)fid * 8) = u.s;
}

// ---- h0 -> fp16 fragment layout in buffer 0; zero barrier counters ----
// (identical layout to v5: unit U=(k>>5)*8+((k>>2)&7), idx=U*256+(M>>4)*16+(M&15))
__global__ __launch_bounds__(256) void prep_state(const float* __restrict__ h0,
                                                  unsigned long long* __restrict__ hb0,
                                                  unsigned int* __restrict__ cnt) {
    int gid = blockIdx.x * 256 + threadIdx.x;   // 0..65535
    int r = gid & 255;
    int U = gid >> 8;
    int kb = (U >> 3) * 32 + ((U >> 1) & 3) * 8 + (U & 1) * 4;
    float4 v = *(const float4*)(h0 + (size_t)r * HH + kb);
    union { _Float16 h[4]; unsigned long long u; } x;
    x.h[0] = (_Float16)v.x; x.h[1] = (_Float16)v.y;
    x.h[2] = (_Float16)v.z; x.h[3] = (_Float16)v.w;
    hb0[(size_t)U * 256 + r] = x.u;
    if (blockIdx.x == 0) cnt[threadIdx.x] = 0;   // 256 u32 = 8 groups x 32
}

// ---- persistent LSTM kernel: all 512 steps + final FC ----
__global__ __launch_bounds__(512, 1) void lstm_persist(
    const float* __restrict__ y_hist,
    const float* __restrict__ W_ih,           // (4096) flat
    const float* __restrict__ b_ih,
    const float* __restrict__ b_hh,
    const float* __restrict__ c0,             // (B,H) f32
    const float* __restrict__ W_fc,           // (H)
    const float* __restrict__ b_fc,           // (1)
    const unsigned short* __restrict__ Wp,    // packed fp16 W fragments
    unsigned long long* hbase,                // 2 buffers x HP_U64 u64
    unsigned int* cnt,
    float* __restrict__ out)
{
    __shared__ __align__(16) unsigned short Wlds[65536];   // 128 KB: gates 0,1
    __shared__ __align__(16) float scr[8192];              // 32 KB: 4 regions x 2048
    // 160 KiB exactly -> 1 WG/CU; grid=256 => all WGs co-resident

    const int tid = threadIdx.x;
    const int lane = tid & 63;
    const int wv = tid >> 6;
    const int m2 = wv & 1;                     // m half (16 rows)
    const int k4 = wv >> 1;                    // K quarter (256 k)
    const int bid = blockIdx.x;
    const int gm = bid >> 5;                   // m-group 0..7 (32 rows)
    const int jt2 = bid & 31;                  // 32-j tile

    const unsigned short* WpJ = Wp + (size_t)jt2 * 131072;

    // --- LDS: gates 0,1 fragments (all kc), straight strided copy ---
    for (int f = tid; f < 8192; f += 512) {
        int kc = f >> 8, g = (f >> 7) & 1, low = f & 127;
        *(short8*)&Wlds[(size_t)((kc * 2 + g) * 128 + low) * 8] =
            *(const short8*)(WpJ + (size_t)((kc * 4 + g) * 128 + low) * 8);
    }
    // --- registers: gates 2,3 fragments for this wave's K-quarter ---
    half8 Breg[8][2][2];   // [kc_l][g-2][nt]
#pragma unroll
    for (int kc_l = 0; kc_l < 8; ++kc_l) {
        int kc = k4 * 8 + kc_l;
#pragma unroll
        for (int g2 = 0; g2 < 2; ++g2)
#pragma unroll
            for (int nt = 0; nt < 2; ++nt)
                Breg[kc_l][g2][nt] = *(const half8*)
                    (WpJ + (size_t)((((kc * 4 + 2 + g2) * 2 + nt) * 64 + lane)) * 8);
    }

    // --- A addressing ---
    const int blk = gm * 2 + m2;               // 16-row block 0..15
    const int q = lane >> 4;
    const size_t abase = (size_t)blk * 16 + (lane & 15);
    const size_t qoff = (size_t)q * 512;

    // --- epilogue constants (tid<256: cell = 1 row x 4 j) ---
    const int em = tid & 31;
    const int jq = (tid >> 5) & 7;
    const int M = gm * 32 + em;
    float wi_[4][4], bs_[4][4], c_[4];
    if (tid < 256) {
#pragma unroll
        for (int g = 0; g < 4; ++g)
#pragma unroll
            for (int jj = 0; jj < 4; ++jj) {
                int j = jt2 * 32 + jq * 4 + jj;
                wi_[g][jj] = W_ih[g * HH + j];
                bs_[g][jj] = b_ih[g * HH + j] + b_hh[g * HH + j];
            }
#pragma unroll
        for (int jj = 0; jj < 4; ++jj)
            c_[jj] = c0[(size_t)M * HH + jt2 * 32 + jq * 4 + jj];
    }
    const size_t sunit = (size_t)(jt2 * 8 + jq) * 256 + (M >> 4) * 16 + (M & 15);

    __syncthreads();   // Wlds visible

    unsigned int* mycnt = cnt + gm * 32;
    const int ml = q * 4;                      // local row base within 16-row tile

    for (int t = 0; t < TT; ++t) {
        const unsigned long long* hR = hbase + (size_t)(t & 1) * HP_U64;
        unsigned long long* hW = hbase + (size_t)((t + 1) & 1) * HP_U64;

        float4v acc[8] = {{0.f,0.f,0.f,0.f},{0.f,0.f,0.f,0.f},{0.f,0.f,0.f,0.f},
                          {0.f,0.f,0.f,0.f},{0.f,0.f,0.f,0.f},{0.f,0.f,0.f,0.f},
                          {0.f,0.f,0.f,0.f},{0.f,0.f,0.f,0.f}};

        // --- sync-free K-loop: 8 chunks of K=32, 4-deep A prefetch ring ---
        unsigned long long ring[4][2];
#pragma unroll
        for (int p = 0; p < 4; ++p) {
            size_t ua = (size_t)(k4 * 8 + p) * 2048 + qoff + abase;
            ring[p][0] = __hip_atomic_load((unsigned long long*)&hR[ua],
                                           __ATOMIC_RELAXED, __HIP_MEMORY_SCOPE_AGENT);
            ring[p][1] = __hip_atomic_load((unsigned long long*)&hR[ua + 256],
                                           __ATOMIC_RELAXED, __HIP_MEMORY_SCOPE_AGENT);
        }
#pragma unroll
        for (int ch = 0; ch < 8; ++ch) {
            union { unsigned long long u[2]; half8 h; } af;
            af.u[0] = ring[ch & 3][0];
            af.u[1] = ring[ch & 3][1];
            if (ch < 4) {
                size_t ua = (size_t)(k4 * 8 + ch + 4) * 2048 + qoff + abase;
                ring[ch & 3][0] = __hip_atomic_load((unsigned long long*)&hR[ua],
                                                    __ATOMIC_RELAXED, __HIP_MEMORY_SCOPE_AGENT);
                ring[ch & 3][1] = __hip_atomic_load((unsigned long long*)&hR[ua + 256],
                                                    __ATOMIC_RELAXED, __HIP_MEMORY_SCOPE_AGENT);
            }
            const int kc = k4 * 8 + ch;
#pragma unroll
            for (int g = 0; g < 2; ++g)
#pragma unroll
                for (int nt = 0; nt < 2; ++nt) {
                    half8 bh = *(const half8*)
                        &Wlds[(size_t)((kc * 2 + g) * 128 + nt * 64 + lane) * 8];
                    acc[g * 2 + nt] =
                        __builtin_amdgcn_mfma_f32_16x16x32_f16(af.h, bh, acc[g * 2 + nt], 0, 0, 0);
                }
#pragma unroll
            for (int g2 = 0; g2 < 2; ++g2)
#pragma unroll
                for (int nt = 0; nt < 2; ++nt)
                    acc[(2 + g2) * 2 + nt] =
                        __builtin_amdgcn_mfma_f32_16x16x32_f16(af.h, Breg[ch][g2][nt],
                                                               acc[(2 + g2) * 2 + nt], 0, 0, 0);
        }

        // --- 4-way k-reduction, 2 rounds in 32 KB scratch ---
        // region r (2048 f32 = 16 rows x 128 n): addr = r*2048 + n*16 + ((m&15)^((n&3)<<2))
        if (k4 >= 2) {
            int rb = (m2 * 2 + (k4 & 1)) * 2048;
#pragma unroll
            for (int a = 0; a < 8; ++a) {
                int n = (a >> 1) * 32 + (a & 1) * 16 + (lane & 15);
                *(float4v*)&scr[rb + n * 16 + (ml ^ ((n & 3) << 2))] = acc[a];
            }
        }
        __syncthreads();
        if (k4 < 2) {
            int rb = (m2 * 2 + k4) * 2048;
#pragma unroll
            for (int a = 0; a < 8; ++a) {
                int n = (a >> 1) * 32 + (a & 1) * 16 + (lane & 15);
                acc[a] += *(const float4v*)&scr[rb + n * 16 + (ml ^ ((n & 3) << 2))];
            }
            if (k4 == 1) {   // write summed partial back (same region just read)
#pragma unroll
                for (int a = 0; a < 8; ++a) {
                    int n = (a >> 1) * 32 + (a & 1) * 16 + (lane & 15);
                    *(float4v*)&scr[(m2 * 2 + 1) * 2048 + n * 16 + (ml ^ ((n & 3) << 2))] = acc[a];
                }
            }
        }
        __syncthreads();
        if (k4 == 0) {   // final add; write G to region m2*2
#pragma unroll
            for (int a = 0; a < 8; ++a) {
                int n = (a >> 1) * 32 + (a & 1) * 16 + (lane & 15);
                int sw = n * 16 + (ml ^ ((n & 3) << 2));
                acc[a] += *(const float4v*)&scr[(m2 * 2 + 1) * 2048 + sw];
                *(float4v*)&scr[(m2 * 2) * 2048 + sw] = acc[a];
            }
        }
        __syncthreads();

        // --- epilogue (tid<256): rows em, j-quad jq; one u64 sc0sc1 store ---
        if (tid < 256) {
            float x = y_hist[(size_t)M * TT + t];
            int rbase = (em >> 4) * 2 * 2048;
            union { _Float16 h[4]; unsigned long long u; } hv;
#pragma unroll
            for (int jj = 0; jj < 4; ++jj) {
                int msw = (em & 15) ^ (jj << 2);   // n&3 == jj for all gates
                int nb = jq * 4 + jj;
                float gi = scr[rbase + (0 * 32 + nb) * 16 + msw] + x * wi_[0][jj] + bs_[0][jj];
                float gf = scr[rbase + (1 * 32 + nb) * 16 + msw] + x * wi_[1][jj] + bs_[1][jj];
                float gg = scr[rbase + (2 * 32 + nb) * 16 + msw] + x * wi_[2][jj] + bs_[2][jj];
                float go = scr[rbase + (3 * 32 + nb) * 16 + msw] + x * wi_[3][jj] + bs_[3][jj];
                float cn = sigf(gf) * c_[jj] + sigf(gi) * tanhff(gg);
                float hn = sigf(go) * tanhff(cn);
                c_[jj] = cn;
                hv.h[jj] = (_Float16)hn;
            }
            asm volatile("global_store_dwordx2 %0, %1, off sc0 sc1"
                         : : "v"((void*)(hW + sunit)), "v"(hv.u) : "memory");
        }

        // --- drain stores, then m-group barrier (32 WGs) ---
        asm volatile("s_waitcnt vmcnt(0)" ::: "memory");
        __syncthreads();
        if (tid == 0) {
            __hip_atomic_fetch_add(mycnt, 1u, __ATOMIC_RELAXED, __HIP_MEMORY_SCOPE_AGENT);
            unsigned target = 32u * (unsigned)(t + 1);
            while (__hip_atomic_load(mycnt, __ATOMIC_RELAXED, __HIP_MEMORY_SCOPE_AGENT) <
                   target)
                __builtin_amdgcn_s_sleep(1);
        }
        __syncthreads();
    }

    // --- final FC (h final in buffer 0): jt2==0 WGs, k4==0 waves ---
    if (jt2 == 0 && k4 == 0) {
        const unsigned long long* hF = hbase;   // buffer 0
#pragma unroll 1
        for (int rr = 0; rr < 16; ++rr) {
            int row = gm * 32 + m2 * 16 + rr;
            int boff = (row >> 4) * 16 + (row & 15);
            float s = 0.f;
#pragma unroll 1
            for (int uu = 0; uu < 4; ++uu) {
                int U = uu * 64 + lane;
                unsigned long long u = __hip_atomic_load(
                    (unsigned long long*)&hF[(size_t)U * 256 + boff],
                    __ATOMIC_RELAXED, __HIP_MEMORY_SCOPE_AGENT);
                int kb = (U >> 3) * 32 + ((U >> 1) & 3) * 8 + (U & 1) * 4;
                union { _Float16 h[4]; unsigned long long x; } v;
                v.x = u;
                float4 wf = *(const float4*)(W_fc + kb);
                s += (float)v.h[0] * wf.x + (float)v.h[1] * wf.y +
                     (float)v.h[2] * wf.z + (float)v.h[3] * wf.w;
            }
#pragma unroll
            for (int off = 32; off > 0; off >>= 1) s += __shfl_xor(s, off);
            if (lane == 0) out[row] = s + b_fc[0];
        }
    }
}

extern "C" void kernel_launch(void* const* d_in, const int* in_sizes, int n_in,
                              void* d_out, int out_size, void* d_ws, size_t ws_size,
                              hipStream_t stream) {
    const float* y_hist = (const float*)d_in[0];
    const float* W_ih   = (const float*)d_in[1];
    const float* W_hh   = (const float*)d_in[2];
    const float* b_ih   = (const float*)d_in[3];
    const float* b_hh   = (const float*)d_in[4];
    const float* W_fc   = (const float*)d_in[5];
    const float* b_fc   = (const float*)d_in[6];
    const float* h0     = (const float*)d_in[7];
    const float* c0     = (const float*)d_in[8];
    float* out = (float*)d_out;

    // ws: Wp fp16 (8 MB) | h buffers 2 x 512 KB | cnt (1 KB)
    unsigned short* Wp = (unsigned short*)d_ws;
    unsigned long long* hbase = (unsigned long long*)(Wp + (size_t)4194304);
    unsigned int* cnt = (unsigned int*)(hbase + 2 * HP_U64);

    pack_w<<<2048, 256, 0, stream>>>(W_hh, Wp);
    prep_state<<<256, 256, 0, stream>>>(h0, hbase, cnt);

    // 256 WGs x 512 threads, 160 KiB LDS -> 1 WG/CU, all co-resident
    lstm_persist<<<256, 512, 0, stream>>>(y_hist, W_ih, b_ih, b_hh, c0, W_fc, b_fc,
                                          Wp, hbase, cnt, out);
}